// Round 2
// baseline (462.238 us; speedup 1.0000x reference)
//
#include <hip/hip_runtime.h>
#include <hip/hip_bf16.h>

#define S_  2048
#define B_  2
#define D_  1024
#define H_  16
#define F_  4096
#define HD_ 64
#define NT_ (S_*B_)   // 4096 tokens

typedef __attribute__((ext_vector_type(8))) short short8;
typedef __attribute__((ext_vector_type(4))) short short4v;
typedef __attribute__((ext_vector_type(4))) float f32x4;

#define MFMA16x16x32(a,b,c) __builtin_amdgcn_mfma_f32_16x16x32_bf16((a),(b),(c),0,0,0)

#define AS1C(p) ((const __attribute__((address_space(1))) void*)(p))
#define AS3(p)  ((__attribute__((address_space(3))) void*)(p))

__device__ __forceinline__ short f2b(float f) {
  union { float f; unsigned u; } x; x.f = f;
  unsigned r = x.u + 0x7FFFu + ((x.u >> 16) & 1u);
  return (short)(r >> 16);
}

// ---------------- elementwise fp32 -> bf16 ----------------
__global__ __launch_bounds__(256) void to_bf16_k(const float* __restrict__ in,
                                                 short* __restrict__ out) {
  int i = (blockIdx.x * 256 + threadIdx.x) * 8;
  float4 a = *(const float4*)(in + i);
  float4 b = *(const float4*)(in + i + 4);
  short8 o;
  o[0] = f2b(a.x); o[1] = f2b(a.y); o[2] = f2b(a.z); o[3] = f2b(a.w);
  o[4] = f2b(b.x); o[5] = f2b(b.y); o[6] = f2b(b.z); o[7] = f2b(b.w);
  *(short8*)(out + i) = o;
}

// ---------------- W[K,N] fp32 -> Wt[(n+colbase)][k] bf16 ----------------
__global__ __launch_bounds__(256) void transpose_to_bf16(const float* __restrict__ W,
                                                         short* __restrict__ Wt,
                                                         int K, int N, int colbase, int outK) {
  __shared__ short t[32][33];
  int tx = threadIdx.x & 31, ty = threadIdx.x >> 5;  // ty 0..7
  int kbase = blockIdx.y * 32, nbase = blockIdx.x * 32;
#pragma unroll
  for (int yy = 0; yy < 4; ++yy) {
    int kk = ty + yy * 8;
    t[kk][tx] = f2b(W[(size_t)(kbase + kk) * N + nbase + tx]);
  }
  __syncthreads();
#pragma unroll
  for (int yy = 0; yy < 4; ++yy) {
    int nn = ty + yy * 8;
    Wt[(size_t)(nbase + nn + colbase) * outK + kbase + tx] = t[tx][nn];
  }
}

// ---------------- GEMM: C[M,N] = A[M,K](bf16) @ Bt[N,K]^T(bf16) + epilogue ----------------
// m97 structure: global_load_lds width-16 staging, linear LDS, 2-barrier K-loop.
// MODE 0: QKV  (bias q/k/v, q scaled 0.125, writes q[b,h,s,d], k[b,h,s,d], v[b,h,d,s] bf16)
// MODE 1: out = acc + bias + resid   (fp32)
// MODE 2: out = relu(acc + bias)     (bf16)
template<int MODE>
__global__ __launch_bounds__(256, 2) void gemm_bt(
    const short* __restrict__ A, const short* __restrict__ Bt,
    int M, int N, int K,
    const float* __restrict__ bias0, const float* __restrict__ bias1,
    const float* __restrict__ bias2,
    const float* __restrict__ resid, float* __restrict__ outf,
    short* __restrict__ outq, short* __restrict__ outk, short* __restrict__ outv) {
  __shared__ __align__(16) short As[128 * 32];
  __shared__ __align__(16) short Bs[128 * 32];
  int tid = threadIdx.x;
  int lane = tid & 63, w = tid >> 6;
  int g = lane >> 4, r = lane & 15;
  int wm = w >> 1, wn = w & 1;
  int row0 = blockIdx.y * 128, col0 = blockIdx.x * 128;

  // staging addresses (constant across K-loop except kt)
  int sidx0 = tid;           // chunk 0
  int sidx1 = tid + 256;     // chunk 1
  int arow0 = sidx0 >> 2, ac0 = (sidx0 & 3) * 8;
  int arow1 = sidx1 >> 2, ac1 = (sidx1 & 3) * 8;

  f32x4 acc[4][4];
#pragma unroll
  for (int m = 0; m < 4; ++m)
#pragma unroll
    for (int n = 0; n < 4; ++n) acc[m][n] = (f32x4){0.f, 0.f, 0.f, 0.f};

  for (int kt = 0; kt < K; kt += 32) {
    // async global -> LDS staging (16B per lane per issue)
    __builtin_amdgcn_global_load_lds(AS1C(A  + (size_t)(row0 + arow0) * K + kt + ac0),
                                     AS3(As + sidx0 * 8), 16, 0, 0);
    __builtin_amdgcn_global_load_lds(AS1C(A  + (size_t)(row0 + arow1) * K + kt + ac1),
                                     AS3(As + sidx1 * 8), 16, 0, 0);
    __builtin_amdgcn_global_load_lds(AS1C(Bt + (size_t)(col0 + arow0) * K + kt + ac0),
                                     AS3(Bs + sidx0 * 8), 16, 0, 0);
    __builtin_amdgcn_global_load_lds(AS1C(Bt + (size_t)(col0 + arow1) * K + kt + ac1),
                                     AS3(Bs + sidx1 * 8), 16, 0, 0);
    __syncthreads();   // drains vmcnt -> tile visible
    short8 af[4], bfr[4];
#pragma unroll
    for (int m = 0; m < 4; ++m) af[m]  = *(const short8*)(As + (wm * 64 + m * 16 + r) * 32 + g * 8);
#pragma unroll
    for (int n = 0; n < 4; ++n) bfr[n] = *(const short8*)(Bs + (wn * 64 + n * 16 + r) * 32 + g * 8);
#pragma unroll
    for (int m = 0; m < 4; ++m)
#pragma unroll
      for (int n = 0; n < 4; ++n)
        acc[m][n] = MFMA16x16x32(af[m], bfr[n], acc[m][n]);
    __syncthreads();   // all waves done reading before next overwrite
  }

  int rb = row0 + wm * 64, cb = col0 + wn * 64;
#pragma unroll
  for (int m = 0; m < 4; ++m) {
#pragma unroll
    for (int n = 0; n < 4; ++n) {
#pragma unroll
      for (int j = 0; j < 4; ++j) {
        int row = rb + m * 16 + g * 4 + j;
        int col = cb + n * 16 + r;
        float v = acc[m][n][j];
        if (MODE == 0) {
          int s = row >> 1, b = row & 1;
          if (col < 1024) {
            float q = (v + bias0[col]) * 0.125f;
            int h = col >> 6, hd = col & 63;
            outq[((size_t)(b * H_ + h) * S_ + s) * HD_ + hd] = f2b(q);
          } else if (col < 2048) {
            int c2 = col - 1024;
            float kk = v + bias1[c2];
            int h = c2 >> 6, hd = c2 & 63;
            outk[((size_t)(b * H_ + h) * S_ + s) * HD_ + hd] = f2b(kk);
          } else {
            int c2 = col - 2048;
            float vv = v + bias2[c2];
            int h = c2 >> 6, hd = c2 & 63;
            outv[((size_t)(b * H_ + h) * HD_ + hd) * S_ + s] = f2b(vv);
          }
        } else if (MODE == 1) {
          size_t o = (size_t)row * N + col;
          outf[o] = v + bias0[col] + resid[o];
        } else {
          size_t o = (size_t)row * N + col;
          float t = v + bias0[col];
          outq[o] = f2b(t > 0.f ? t : 0.f);
        }
      }
    }
  }
}

// ---------------- flash attention, swapped-operand form ----------------
// Q,K: [b*H+h][s][d] bf16 (Q pre-scaled), Vt: [b*H+h][d][s] bf16
// S^T = mfma(K, Q): lane owns one q-row (col=r) -> softmax nearly lane-local.
// ctx^T = mfma(V^T, P^T). ctx out token-major [s*B+b][h*64+hd] bf16.
// 4 waves x 16 q-rows = 64 q/block; grid 1024 blocks (4/CU, 16 waves/CU).
__global__ __launch_bounds__(256, 4) void flash_attn(const short* __restrict__ Q,
                                                     const short* __restrict__ Kb,
                                                     const short* __restrict__ Vt,
                                                     short* __restrict__ ctx) {
  __shared__ __align__(16) short P[4][16][40];
  int lane = threadIdx.x & 63, w = threadIdx.x >> 6;
  int g = lane >> 4, r = lane & 15;
  // bijective XCD swizzle: XCD x gets bh in {4x..4x+3} -> 2MB K/V working set per L2
  int f = blockIdx.x;
  int xcd = f & 7, loc = f >> 3;
  int bh = xcd * 4 + (loc >> 5);
  int qt = loc & 31;
  const short* qp = Q  + (size_t)bh * S_ * HD_;
  const short* kp = Kb + (size_t)bh * S_ * HD_;
  const short* vp = Vt + (size_t)bh * HD_ * S_;
  int q0 = qt * 64 + w * 16;

  // Q fragments (B-operand): lane (g,r) elem i = Q[q0+r][kk*32+g*8+i]
  short8 qf[2];
#pragma unroll
  for (int kk = 0; kk < 2; ++kk)
    qf[kk] = *(const short8*)(qp + (size_t)(q0 + r) * HD_ + kk * 32 + g * 8);

  f32x4 acc[4];   // ctx^T fragments: [d-block]; col=q(=r), row=d_local
#pragma unroll
  for (int db = 0; db < 4; ++db) acc[db] = (f32x4){0.f, 0.f, 0.f, 0.f};
  float mi = -1e30f, li = 0.f;

  for (int kv0 = 0; kv0 < S_; kv0 += 32) {
    // K fragments (A-operand): lane elem i = K[kv0+kb*16+r][kk*32+g*8+i]
    short8 kf[2][2];
#pragma unroll
    for (int kb = 0; kb < 2; ++kb)
#pragma unroll
      for (int kk = 0; kk < 2; ++kk)
        kf[kb][kk] = *(const short8*)(kp + (size_t)(kv0 + kb * 16 + r) * HD_ + kk * 32 + g * 8);
    // V^T fragments (A-operand), independent of softmax -> compiler hoists loads
    short8 vf[4];
#pragma unroll
    for (int db = 0; db < 4; ++db)
      vf[db] = *(const short8*)(vp + (size_t)(db * 16 + r) * S_ + kv0 + g * 8);

    // S^T[k_local][q]: st[kb], value at (k=kv0+kb*16+g*4+j, q=q0+r)
    f32x4 st[2];
#pragma unroll
    for (int kb = 0; kb < 2; ++kb) {
      f32x4 t = (f32x4){0.f, 0.f, 0.f, 0.f};
      t = MFMA16x16x32(kf[kb][0], qf[0], t);
      t = MFMA16x16x32(kf[kb][1], qf[1], t);
      st[kb] = t;
    }

    // online softmax for q=q0+r: 8 in-lane values + reduce across g (2 shfls)
    float pm = st[0][0];
    pm = fmaxf(pm, st[0][1]); pm = fmaxf(pm, st[0][2]); pm = fmaxf(pm, st[0][3]);
    pm = fmaxf(pm, st[1][0]); pm = fmaxf(pm, st[1][1]);
    pm = fmaxf(pm, st[1][2]); pm = fmaxf(pm, st[1][3]);
    pm = fmaxf(pm, __shfl_xor(pm, 16));
    pm = fmaxf(pm, __shfl_xor(pm, 32));
    float mn = fmaxf(mi, pm);
    float sc = __expf(mi - mn);
    mi = mn;
    float e[2][4];
    float rs = 0.f;
#pragma unroll
    for (int kb = 0; kb < 2; ++kb)
#pragma unroll
      for (int j = 0; j < 4; ++j) {
        float p0 = __expf(st[kb][j] - mn);
        e[kb][j] = p0;
        rs += p0;
      }
    rs += __shfl_xor(rs, 16);
    rs += __shfl_xor(rs, 32);
    li = li * sc + rs;
#pragma unroll
    for (int db = 0; db < 4; ++db)
#pragma unroll
      for (int j = 0; j < 4; ++j) acc[db][j] *= sc;   // sc lane-uniform (one q/lane)

    // P stored [q][k] so P^T B-fragment read is a contiguous short8
#pragma unroll
    for (int kb = 0; kb < 2; ++kb) {
      short4v pw;
      pw[0] = f2b(e[kb][0]); pw[1] = f2b(e[kb][1]);
      pw[2] = f2b(e[kb][2]); pw[3] = f2b(e[kb][3]);
      *(short4v*)&P[w][r][kb * 16 + g * 4] = pw;
    }
    short8 pf = *(const short8*)&P[w][r][g * 8];   // B: elem i = P^T[g*8+i][r]

#pragma unroll
    for (int db = 0; db < 4; ++db)
      acc[db] = MFMA16x16x32(vf[db], pf, acc[db]);
  }

  int b = bh >> 4, h = bh & 15;
  float inv = 1.0f / li;
  int s = q0 + r;
  int token = s * B_ + b;
#pragma unroll
  for (int db = 0; db < 4; ++db)
#pragma unroll
    for (int j = 0; j < 4; ++j) {
      int col = h * 64 + db * 16 + g * 4 + j;
      ctx[(size_t)token * D_ + col] = f2b(acc[db][j] * inv);
    }
}

// ---------------- layernorm (row = 1024 fp32), optional bf16 copy ----------------
__global__ __launch_bounds__(256) void layernorm_k(const float* __restrict__ y,
                                                   const float* __restrict__ gm,
                                                   const float* __restrict__ bt,
                                                   float* __restrict__ of,
                                                   short* __restrict__ ob, int writeb) {
  __shared__ float r1[4], r2[4];
  int row = blockIdx.x, tid = threadIdx.x;
  const float* yr = y + (size_t)row * D_;
  float4 v = *(const float4*)(yr + tid * 4);
  float s1 = v.x + v.y + v.z + v.w;
  float s2 = v.x * v.x + v.y * v.y + v.z * v.z + v.w * v.w;
#pragma unroll
  for (int off = 32; off > 0; off >>= 1) {
    s1 += __shfl_xor(s1, off, 64);
    s2 += __shfl_xor(s2, off, 64);
  }
  int wid = tid >> 6;
  if ((tid & 63) == 0) { r1[wid] = s1; r2[wid] = s2; }
  __syncthreads();
  s1 = r1[0] + r1[1] + r1[2] + r1[3];
  s2 = r2[0] + r2[1] + r2[2] + r2[3];
  float mean = s1 * (1.0f / D_);
  float var = s2 * (1.0f / D_) - mean * mean;
  float rstd = rsqrtf(var + 1e-5f);
  float4 gv = *(const float4*)(gm + tid * 4);
  float4 bv = *(const float4*)(bt + tid * 4);
  float o0 = (v.x - mean) * rstd * gv.x + bv.x;
  float o1 = (v.y - mean) * rstd * gv.y + bv.y;
  float o2 = (v.z - mean) * rstd * gv.z + bv.z;
  float o3 = (v.w - mean) * rstd * gv.w + bv.w;
  float4* op = (float4*)(of + (size_t)row * D_ + tid * 4);
  *op = make_float4(o0, o1, o2, o3);
  if (writeb) {
    short4v o;
    o[0] = f2b(o0); o[1] = f2b(o1); o[2] = f2b(o2); o[3] = f2b(o3);
    *(short4v*)(ob + (size_t)row * D_ + tid * 4) = o;
  }
}

extern "C" void kernel_launch(void* const* d_in, const int* in_sizes, int n_in,
                              void* d_out, int out_size, void* d_ws, size_t ws_size,
                              hipStream_t stream) {
  const float* src = (const float*)d_in[0];
  const float* Wq  = (const float*)d_in[1];
  const float* bq  = (const float*)d_in[2];
  const float* Wk  = (const float*)d_in[3];
  const float* bk  = (const float*)d_in[4];
  const float* Wv  = (const float*)d_in[5];
  const float* bv  = (const float*)d_in[6];
  const float* Wo  = (const float*)d_in[7];
  const float* bo  = (const float*)d_in[8];
  const float* g1  = (const float*)d_in[9];
  const float* be1 = (const float*)d_in[10];
  const float* W1  = (const float*)d_in[11];
  const float* bf1 = (const float*)d_in[12];
  const float* W2  = (const float*)d_in[13];
  const float* bf2 = (const float*)d_in[14];
  const float* g2  = (const float*)d_in[15];
  const float* be2 = (const float*)d_in[16];
  float* out = (float*)d_out;
  char* ws = (char*)d_ws;

  // workspace layout (bytes), lifetime-overlapped; total 104 MiB
  short* Wqkv_t = (short*)(ws + 0);          // 6 MiB  [3072][1024]
  short* Wo_t   = (short*)(ws + 6291456);    // 2 MiB  [1024][1024]
  short* W1_t   = (short*)(ws + 8388608);    // 8 MiB  [4096][1024]
  short* W2_t   = (short*)(ws + 16777216);   // 8 MiB  [1024][4096]
  short* xb     = (short*)(ws + 25165824);   // 8 MiB  src bf16
  short* ctx    = (short*)(ws + 33554432);   // 8 MiB
  float* res1   = (float*)(ws + 41943040);   // 16 MiB
  short* hid    = (short*)(ws + 25165824);   // 32 MiB, overlays xb|ctx|res1 (all dead)
  short* qb_    = (short*)(ws + 58720256);   // 8 MiB
  short* kb_    = (short*)(ws + 67108864);   // 8 MiB
  float* res2   = (float*)(ws + 58720256);   // 16 MiB, overlays q|k (dead)
  short* vb_    = (short*)(ws + 75497472);   // 8 MiB
  float* x1f    = (float*)(ws + 83886080);   // 16 MiB
  short* x1b    = (short*)(ws + 100663296);  // 8 MiB   (end: 109051904)

  to_bf16_k<<<2048, 256, 0, stream>>>(src, xb);

  transpose_to_bf16<<<dim3(32, 32),  256, 0, stream>>>(Wq, Wqkv_t, 1024, 1024, 0,    1024);
  transpose_to_bf16<<<dim3(32, 32),  256, 0, stream>>>(Wk, Wqkv_t, 1024, 1024, 1024, 1024);
  transpose_to_bf16<<<dim3(32, 32),  256, 0, stream>>>(Wv, Wqkv_t, 1024, 1024, 2048, 1024);
  transpose_to_bf16<<<dim3(32, 32),  256, 0, stream>>>(Wo, Wo_t,   1024, 1024, 0,    1024);
  transpose_to_bf16<<<dim3(128, 32), 256, 0, stream>>>(W1, W1_t,   1024, 4096, 0,    1024);
  transpose_to_bf16<<<dim3(32, 128), 256, 0, stream>>>(W2, W2_t,   4096, 1024, 0,    4096);

  // QKV projection (M=4096, N=3072, K=1024)
  gemm_bt<0><<<dim3(24, 32), 256, 0, stream>>>(xb, Wqkv_t, NT_, 3072, 1024,
                                               bq, bk, bv, nullptr, nullptr, qb_, kb_, vb_);
  // attention (1024 blocks, XCD-swizzled)
  flash_attn<<<1024, 256, 0, stream>>>(qb_, kb_, vb_, ctx);
  // out-proj + residual(src) -> res1
  gemm_bt<1><<<dim3(8, 32), 256, 0, stream>>>(ctx, Wo_t, NT_, 1024, 1024,
                                              bo, nullptr, nullptr, src, res1,
                                              nullptr, nullptr, nullptr);
  // LN1 -> x1f (fp32) + x1b (bf16)
  layernorm_k<<<NT_, 256, 0, stream>>>(res1, g1, be1, x1f, x1b, 1);
  // FFN1 + ReLU -> hid (bf16, M=4096, N=4096, K=1024)
  gemm_bt<2><<<dim3(32, 32), 256, 0, stream>>>(x1b, W1_t, NT_, 4096, 1024,
                                               bf1, nullptr, nullptr, nullptr, nullptr,
                                               hid, nullptr, nullptr);
  // FFN2 + residual(x1f) -> res2 (M=4096, N=1024, K=4096)
  gemm_bt<1><<<dim3(8, 32), 256, 0, stream>>>(hid, W2_t, NT_, 1024, 4096,
                                              bf2, nullptr, nullptr, x1f, res2,
                                              nullptr, nullptr, nullptr);
  // LN2 -> out
  layernorm_k<<<NT_, 256, 0, stream>>>(res2, g2, be2, out, nullptr, 0);
}

// Round 3
// 276.559 us; speedup vs baseline: 1.6714x; 1.6714x over previous
//
#include <hip/hip_runtime.h>
#include <hip/hip_bf16.h>

#define S_  2048
#define B_  2
#define D_  1024
#define H_  16
#define F_  4096
#define HD_ 64
#define NT_ (S_*B_)   // 4096 tokens

typedef __attribute__((ext_vector_type(8))) short short8;
typedef __attribute__((ext_vector_type(4))) short short4v;
typedef __attribute__((ext_vector_type(4))) float f32x4;

#define MFMA16x16x32(a,b,c) __builtin_amdgcn_mfma_f32_16x16x32_bf16((a),(b),(c),0,0,0)

#define AS1C(p) ((const __attribute__((address_space(1))) void*)(p))
#define AS3(p)  ((__attribute__((address_space(3))) void*)(p))

__device__ __forceinline__ short f2b(float f) {
  union { float f; unsigned u; } x; x.f = f;
  unsigned r = x.u + 0x7FFFu + ((x.u >> 16) & 1u);
  return (short)(r >> 16);
}

// ---------------- elementwise fp32 -> bf16 ----------------
__global__ __launch_bounds__(256) void to_bf16_k(const float* __restrict__ in,
                                                 short* __restrict__ out) {
  int i = (blockIdx.x * 256 + threadIdx.x) * 8;
  float4 a = *(const float4*)(in + i);
  float4 b = *(const float4*)(in + i + 4);
  short8 o;
  o[0] = f2b(a.x); o[1] = f2b(a.y); o[2] = f2b(a.z); o[3] = f2b(a.w);
  o[4] = f2b(b.x); o[5] = f2b(b.y); o[6] = f2b(b.z); o[7] = f2b(b.w);
  *(short8*)(out + i) = o;
}

// ---------------- W[K,N] fp32 -> Wt[(n+colbase)][k] bf16 ----------------
__global__ __launch_bounds__(256) void transpose_to_bf16(const float* __restrict__ W,
                                                         short* __restrict__ Wt,
                                                         int K, int N, int colbase, int outK) {
  __shared__ short t[32][33];
  int tx = threadIdx.x & 31, ty = threadIdx.x >> 5;  // ty 0..7
  int kbase = blockIdx.y * 32, nbase = blockIdx.x * 32;
#pragma unroll
  for (int yy = 0; yy < 4; ++yy) {
    int kk = ty + yy * 8;
    t[kk][tx] = f2b(W[(size_t)(kbase + kk) * N + nbase + tx]);
  }
  __syncthreads();
#pragma unroll
  for (int yy = 0; yy < 4; ++yy) {
    int nn = ty + yy * 8;
    Wt[(size_t)(nbase + nn + colbase) * outK + kbase + tx] = t[tx][nn];
  }
}

// ---------------- GEMM: C[M,N] = A[M,K](bf16) @ Bt[N,K]^T(bf16) + epilogue ----------------
// m97 structure: BK=64, global_load_lds width-16, linear LDS dest with
// inverse-swizzled source + XOR-swizzled ds_read (T2, rule #21).
// MODE 0: QKV  (bias q/k/v, q scaled 0.125, writes q[b,h,s,d], k[b,h,s,d], v[b,h,d,s] bf16)
// MODE 1: out = acc + bias + resid   (fp32)
// MODE 2: out = relu(acc + bias)     (bf16)
template<int MODE>
__global__ __launch_bounds__(256, 2) void gemm_bt(
    const short* __restrict__ A, const short* __restrict__ Bt,
    int M, int N, int K,
    const float* __restrict__ bias0, const float* __restrict__ bias1,
    const float* __restrict__ bias2,
    const float* __restrict__ resid, float* __restrict__ outf,
    short* __restrict__ outq, short* __restrict__ outk, short* __restrict__ outv) {
  __shared__ __align__(16) short As[128 * 64];
  __shared__ __align__(16) short Bs[128 * 64];
  int tid = threadIdx.x;
  int lane = tid & 63, w = tid >> 6;
  int g = lane >> 4, r = lane & 15;
  int wm = w >> 1, wn = w & 1;
  int row0 = blockIdx.y * 128, col0 = blockIdx.x * 128;

  f32x4 acc[4][4];
#pragma unroll
  for (int m = 0; m < 4; ++m)
#pragma unroll
    for (int n = 0; n < 4; ++n) acc[m][n] = (f32x4){0.f, 0.f, 0.f, 0.f};

  for (int kt = 0; kt < K; kt += 64) {
    // stage 128x64 tiles; LDS dest linear (wave-uniform+lane*16), source
    // column pre-swizzled so a swizzled READ sees the right data
#pragma unroll
    for (int p = 0; p < 4; ++p) {
      int idx = tid + p * 256;
      int row = idx >> 3, c = idx & 7;
      int scol = ((c ^ (row & 7)) << 3);
      __builtin_amdgcn_global_load_lds(AS1C(A  + (size_t)(row0 + row) * K + kt + scol),
                                       AS3(As + idx * 8), 16, 0, 0);
      __builtin_amdgcn_global_load_lds(AS1C(Bt + (size_t)(col0 + row) * K + kt + scol),
                                       AS3(Bs + idx * 8), 16, 0, 0);
    }
    __syncthreads();   // drains vmcnt -> tile visible
    short8 af[4][2], bfr[4][2];
#pragma unroll
    for (int m = 0; m < 4; ++m)
#pragma unroll
      for (int kk = 0; kk < 2; ++kk) {
        int row = wm * 64 + m * 16 + r;
        af[m][kk] = *(const short8*)(As + row * 64 + (((kk * 4 + g) ^ (r & 7)) << 3));
      }
#pragma unroll
    for (int n = 0; n < 4; ++n)
#pragma unroll
      for (int kk = 0; kk < 2; ++kk) {
        int row = wn * 64 + n * 16 + r;
        bfr[n][kk] = *(const short8*)(Bs + row * 64 + (((kk * 4 + g) ^ (r & 7)) << 3));
      }
#pragma unroll
    for (int m = 0; m < 4; ++m)
#pragma unroll
      for (int n = 0; n < 4; ++n)
#pragma unroll
        for (int kk = 0; kk < 2; ++kk)
          acc[m][n] = MFMA16x16x32(af[m][kk], bfr[n][kk], acc[m][n]);
    __syncthreads();   // all waves done reading before next overwrite
  }

  int rb = row0 + wm * 64, cb = col0 + wn * 64;
#pragma unroll
  for (int m = 0; m < 4; ++m) {
#pragma unroll
    for (int n = 0; n < 4; ++n) {
#pragma unroll
      for (int j = 0; j < 4; ++j) {
        int row = rb + m * 16 + g * 4 + j;
        int col = cb + n * 16 + r;
        float v = acc[m][n][j];
        if (MODE == 0) {
          int s = row >> 1, b = row & 1;
          if (col < 1024) {
            float q = (v + bias0[col]) * 0.125f;
            int h = col >> 6, hd = col & 63;
            outq[((size_t)(b * H_ + h) * S_ + s) * HD_ + hd] = f2b(q);
          } else if (col < 2048) {
            int c2 = col - 1024;
            float kk = v + bias1[c2];
            int h = c2 >> 6, hd = c2 & 63;
            outk[((size_t)(b * H_ + h) * S_ + s) * HD_ + hd] = f2b(kk);
          } else {
            int c2 = col - 2048;
            float vv = v + bias2[c2];
            int h = c2 >> 6, hd = c2 & 63;
            outv[((size_t)(b * H_ + h) * HD_ + hd) * S_ + s] = f2b(vv);
          }
        } else if (MODE == 1) {
          size_t o = (size_t)row * N + col;
          outf[o] = v + bias0[col] + resid[o];
        } else {
          size_t o = (size_t)row * N + col;
          float t = v + bias0[col];
          outq[o] = f2b(t > 0.f ? t : 0.f);
        }
      }
    }
  }
}

// ---------------- flash attention, swapped-operand + LDS-staged K/V ----------------
// Q,K: [b*H+h][s][d] bf16 (Q pre-scaled), Vt: [b*H+h][d][s] bf16
// S^T = mfma(K, Q): lane owns one q-row per 16-q fragment -> softmax lane-local.
// ctx^T = mfma(V^T, P^T). 4 waves x 32 q = 128 q/block; KV tile 64, double-buffered
// LDS with XOR swizzle (inverse-swizzled global_load_lds source).
__global__ __launch_bounds__(256, 2) void flash_attn(const short* __restrict__ Q,
                                                     const short* __restrict__ Kb,
                                                     const short* __restrict__ Vt,
                                                     short* __restrict__ ctx) {
  __shared__ __align__(16) short Ks[2][64 * 64];
  __shared__ __align__(16) short Vs[2][64 * 64];
  __shared__ __align__(16) short P[4][32][72];
  int tid = threadIdx.x;
  int lane = tid & 63, w = tid >> 6;
  int g = lane >> 4, r = lane & 15;
  // bijective XCD swizzle: XCD x owns bh in {4x..4x+3} -> 2MB K/V per L2
  int f = blockIdx.x;
  int xcd = f & 7, loc = f >> 3;          // 512 blocks: loc 0..63
  int bh = xcd * 4 + (loc >> 4);
  int qt = loc & 15;
  const short* qp = Q  + (size_t)bh * S_ * HD_;
  const short* kp = Kb + (size_t)bh * S_ * HD_;
  const short* vp = Vt + (size_t)bh * HD_ * S_;
  int q0 = qt * 128 + w * 32;

  // Q B-operand frags: qf[fq][kk] elem i = Q[q0+fq*16+r][kk*32+g*8+i]
  short8 qf[2][2];
#pragma unroll
  for (int fq = 0; fq < 2; ++fq)
#pragma unroll
    for (int kk = 0; kk < 2; ++kk)
      qf[fq][kk] = *(const short8*)(qp + (size_t)(q0 + fq * 16 + r) * HD_ + kk * 32 + g * 8);

  f32x4 acc[2][4];
  float mi[2], li[2];
#pragma unroll
  for (int fq = 0; fq < 2; ++fq) {
    mi[fq] = -1e30f; li[fq] = 0.f;
#pragma unroll
    for (int db = 0; db < 4; ++db) acc[fq][db] = (f32x4){0.f, 0.f, 0.f, 0.f};
  }

  // prologue: stage tile 0 into buf 0
#pragma unroll
  for (int p = 0; p < 2; ++p) {
    int idx = tid + p * 256;
    int row = idx >> 3, c = idx & 7;
    int scol = ((c ^ (row & 7)) << 3);
    __builtin_amdgcn_global_load_lds(AS1C(kp + (size_t)row * HD_ + scol),
                                     AS3(&Ks[0][0] + idx * 8), 16, 0, 0);
    __builtin_amdgcn_global_load_lds(AS1C(vp + (size_t)row * S_ + scol),
                                     AS3(&Vs[0][0] + idx * 8), 16, 0, 0);
  }
  __syncthreads();

  int cur = 0;
  for (int t = 0; t < S_ / 64; ++t) {
    // prefetch tile t+1 into the other buffer (issue-early; barrier at end drains)
    if (t + 1 < S_ / 64) {
      int kv1 = (t + 1) * 64;
#pragma unroll
      for (int p = 0; p < 2; ++p) {
        int idx = tid + p * 256;
        int row = idx >> 3, c = idx & 7;
        int scol = ((c ^ (row & 7)) << 3);
        __builtin_amdgcn_global_load_lds(AS1C(kp + (size_t)(kv1 + row) * HD_ + scol),
                                         AS3(&Ks[cur ^ 1][0] + idx * 8), 16, 0, 0);
        __builtin_amdgcn_global_load_lds(AS1C(vp + (size_t)row * S_ + kv1 + scol),
                                         AS3(&Vs[cur ^ 1][0] + idx * 8), 16, 0, 0);
      }
    }
    const short* Kc = &Ks[cur][0];
    const short* Vc = &Vs[cur][0];
    // K A-operand frags: kf[kb][kk] elem i = K[t*64+kb*16+r][kk*32+g*8+i]
    short8 kf[4][2], vf[4][2];
#pragma unroll
    for (int kb = 0; kb < 4; ++kb)
#pragma unroll
      for (int kk = 0; kk < 2; ++kk) {
        int row = kb * 16 + r;
        kf[kb][kk] = *(const short8*)(Kc + row * 64 + (((kk * 4 + g) ^ (r & 7)) << 3));
      }
#pragma unroll
    for (int db = 0; db < 4; ++db)
#pragma unroll
      for (int ks = 0; ks < 2; ++ks) {
        int row = db * 16 + r;
        vf[db][ks] = *(const short8*)(Vc + row * 64 + (((ks * 4 + g) ^ (r & 7)) << 3));
      }

    // S^T[kv][q]: st[fq][kb], value at (kv = kb*16+g*4+j, q = q0+fq*16+r)
    f32x4 st[2][4];
#pragma unroll
    for (int fq = 0; fq < 2; ++fq)
#pragma unroll
      for (int kb = 0; kb < 4; ++kb) {
        f32x4 tt = (f32x4){0.f, 0.f, 0.f, 0.f};
        tt = MFMA16x16x32(kf[kb][0], qf[fq][0], tt);
        tt = MFMA16x16x32(kf[kb][1], qf[fq][1], tt);
        st[fq][kb] = tt;
      }

    // online softmax (per lane: q-row fq*16+r; 16 in-lane + cross-g reduce)
#pragma unroll
    for (int fq = 0; fq < 2; ++fq) {
      float pm = st[fq][0][0];
#pragma unroll
      for (int kb = 0; kb < 4; ++kb)
#pragma unroll
        for (int j = 0; j < 4; ++j) pm = fmaxf(pm, st[fq][kb][j]);
      pm = fmaxf(pm, __shfl_xor(pm, 16));
      pm = fmaxf(pm, __shfl_xor(pm, 32));
      float mn = fmaxf(mi[fq], pm);
      float sc = __expf(mi[fq] - mn);
      mi[fq] = mn;
      float rs = 0.f;
#pragma unroll
      for (int kb = 0; kb < 4; ++kb)
#pragma unroll
        for (int j = 0; j < 4; ++j) {
          float p0 = __expf(st[fq][kb][j] - mn);
          st[fq][kb][j] = p0;
          rs += p0;
        }
      rs += __shfl_xor(rs, 16);
      rs += __shfl_xor(rs, 32);
      li[fq] = li[fq] * sc + rs;
#pragma unroll
      for (int db = 0; db < 4; ++db)
#pragma unroll
        for (int j = 0; j < 4; ++j) acc[fq][db][j] *= sc;

      // P stored [q][kv] so P^T B-frag read is contiguous short8
#pragma unroll
      for (int kb = 0; kb < 4; ++kb) {
        short4v pw;
        pw[0] = f2b(st[fq][kb][0]); pw[1] = f2b(st[fq][kb][1]);
        pw[2] = f2b(st[fq][kb][2]); pw[3] = f2b(st[fq][kb][3]);
        *(short4v*)&P[w][fq * 16 + r][kb * 16 + g * 4] = pw;
      }
    }

    short8 pf[2][2];
#pragma unroll
    for (int fq = 0; fq < 2; ++fq)
#pragma unroll
      for (int ks = 0; ks < 2; ++ks)
        pf[fq][ks] = *(const short8*)&P[w][fq * 16 + r][ks * 32 + g * 8];

#pragma unroll
    for (int fq = 0; fq < 2; ++fq)
#pragma unroll
      for (int db = 0; db < 4; ++db) {
        acc[fq][db] = MFMA16x16x32(vf[db][0], pf[fq][0], acc[fq][db]);
        acc[fq][db] = MFMA16x16x32(vf[db][1], pf[fq][1], acc[fq][db]);
      }

    __syncthreads();   // drains prefetch (vmcnt0) + protects buffer swap
    cur ^= 1;
  }

  int b = bh >> 4, h = bh & 15;
#pragma unroll
  for (int fq = 0; fq < 2; ++fq) {
    float inv = 1.0f / li[fq];
    int s = q0 + fq * 16 + r;
    int token = s * B_ + b;
#pragma unroll
    for (int db = 0; db < 4; ++db) {
      short4v o;
#pragma unroll
      for (int j = 0; j < 4; ++j) o[j] = f2b(acc[fq][db][j] * inv);
      *(short4v*)(ctx + (size_t)token * D_ + h * 64 + db * 16 + g * 4) = o;
    }
  }
}

// ---------------- layernorm (row = 1024 fp32), optional bf16 copy ----------------
__global__ __launch_bounds__(256) void layernorm_k(const float* __restrict__ y,
                                                   const float* __restrict__ gm,
                                                   const float* __restrict__ bt,
                                                   float* __restrict__ of,
                                                   short* __restrict__ ob, int writeb) {
  __shared__ float r1[4], r2[4];
  int row = blockIdx.x, tid = threadIdx.x;
  const float* yr = y + (size_t)row * D_;
  float4 v = *(const float4*)(yr + tid * 4);
  float s1 = v.x + v.y + v.z + v.w;
  float s2 = v.x * v.x + v.y * v.y + v.z * v.z + v.w * v.w;
#pragma unroll
  for (int off = 32; off > 0; off >>= 1) {
    s1 += __shfl_xor(s1, off, 64);
    s2 += __shfl_xor(s2, off, 64);
  }
  int wid = tid >> 6;
  if ((tid & 63) == 0) { r1[wid] = s1; r2[wid] = s2; }
  __syncthreads();
  s1 = r1[0] + r1[1] + r1[2] + r1[3];
  s2 = r2[0] + r2[1] + r2[2] + r2[3];
  float mean = s1 * (1.0f / D_);
  float var = s2 * (1.0f / D_) - mean * mean;
  float rstd = rsqrtf(var + 1e-5f);
  float4 gv = *(const float4*)(gm + tid * 4);
  float4 bv = *(const float4*)(bt + tid * 4);
  float o0 = (v.x - mean) * rstd * gv.x + bv.x;
  float o1 = (v.y - mean) * rstd * gv.y + bv.y;
  float o2 = (v.z - mean) * rstd * gv.z + bv.z;
  float o3 = (v.w - mean) * rstd * gv.w + bv.w;
  float4* op = (float4*)(of + (size_t)row * D_ + tid * 4);
  *op = make_float4(o0, o1, o2, o3);
  if (writeb) {
    short4v o;
    o[0] = f2b(o0); o[1] = f2b(o1); o[2] = f2b(o2); o[3] = f2b(o3);
    *(short4v*)(ob + (size_t)row * D_ + tid * 4) = o;
  }
}

extern "C" void kernel_launch(void* const* d_in, const int* in_sizes, int n_in,
                              void* d_out, int out_size, void* d_ws, size_t ws_size,
                              hipStream_t stream) {
  const float* src = (const float*)d_in[0];
  const float* Wq  = (const float*)d_in[1];
  const float* bq  = (const float*)d_in[2];
  const float* Wk  = (const float*)d_in[3];
  const float* bk  = (const float*)d_in[4];
  const float* Wv  = (const float*)d_in[5];
  const float* bv  = (const float*)d_in[6];
  const float* Wo  = (const float*)d_in[7];
  const float* bo  = (const float*)d_in[8];
  const float* g1  = (const float*)d_in[9];
  const float* be1 = (const float*)d_in[10];
  const float* W1  = (const float*)d_in[11];
  const float* bf1 = (const float*)d_in[12];
  const float* W2  = (const float*)d_in[13];
  const float* bf2 = (const float*)d_in[14];
  const float* g2  = (const float*)d_in[15];
  const float* be2 = (const float*)d_in[16];
  float* out = (float*)d_out;
  char* ws = (char*)d_ws;

  // workspace layout (bytes), lifetime-overlapped; total 104 MiB
  short* Wqkv_t = (short*)(ws + 0);          // 6 MiB  [3072][1024]
  short* Wo_t   = (short*)(ws + 6291456);    // 2 MiB  [1024][1024]
  short* W1_t   = (short*)(ws + 8388608);    // 8 MiB  [4096][1024]
  short* W2_t   = (short*)(ws + 16777216);   // 8 MiB  [1024][4096]
  short* xb     = (short*)(ws + 25165824);   // 8 MiB  src bf16
  short* ctx    = (short*)(ws + 33554432);   // 8 MiB
  float* res1   = (float*)(ws + 41943040);   // 16 MiB
  short* hid    = (short*)(ws + 25165824);   // 32 MiB, overlays xb|ctx|res1 (all dead)
  short* qb_    = (short*)(ws + 58720256);   // 8 MiB
  short* kb_    = (short*)(ws + 67108864);   // 8 MiB
  float* res2   = (float*)(ws + 58720256);   // 16 MiB, overlays q|k (dead)
  short* vb_    = (short*)(ws + 75497472);   // 8 MiB
  float* x1f    = (float*)(ws + 83886080);   // 16 MiB
  short* x1b    = (short*)(ws + 100663296);  // 8 MiB   (end: 109051904)

  to_bf16_k<<<2048, 256, 0, stream>>>(src, xb);

  transpose_to_bf16<<<dim3(32, 32),  256, 0, stream>>>(Wq, Wqkv_t, 1024, 1024, 0,    1024);
  transpose_to_bf16<<<dim3(32, 32),  256, 0, stream>>>(Wk, Wqkv_t, 1024, 1024, 1024, 1024);
  transpose_to_bf16<<<dim3(32, 32),  256, 0, stream>>>(Wv, Wqkv_t, 1024, 1024, 2048, 1024);
  transpose_to_bf16<<<dim3(32, 32),  256, 0, stream>>>(Wo, Wo_t,   1024, 1024, 0,    1024);
  transpose_to_bf16<<<dim3(128, 32), 256, 0, stream>>>(W1, W1_t,   1024, 4096, 0,    1024);
  transpose_to_bf16<<<dim3(32, 128), 256, 0, stream>>>(W2, W2_t,   4096, 1024, 0,    4096);

  // QKV projection (M=4096, N=3072, K=1024)
  gemm_bt<0><<<dim3(24, 32), 256, 0, stream>>>(xb, Wqkv_t, NT_, 3072, 1024,
                                               bq, bk, bv, nullptr, nullptr, qb_, kb_, vb_);
  // attention (512 blocks, XCD-swizzled, 128 q/block)
  flash_attn<<<512, 256, 0, stream>>>(qb_, kb_, vb_, ctx);
  // out-proj + residual(src) -> res1
  gemm_bt<1><<<dim3(8, 32), 256, 0, stream>>>(ctx, Wo_t, NT_, 1024, 1024,
                                              bo, nullptr, nullptr, src, res1,
                                              nullptr, nullptr, nullptr);
  // LN1 -> x1f (fp32) + x1b (bf16)
  layernorm_k<<<NT_, 256, 0, stream>>>(res1, g1, be1, x1f, x1b, 1);
  // FFN1 + ReLU -> hid (bf16, M=4096, N=4096, K=1024)
  gemm_bt<2><<<dim3(32, 32), 256, 0, stream>>>(x1b, W1_t, NT_, 4096, 1024,
                                               bf1, nullptr, nullptr, nullptr, nullptr,
                                               hid, nullptr, nullptr);
  // FFN2 + residual(x1f) -> res2 (M=4096, N=1024, K=4096)
  gemm_bt<1><<<dim3(8, 32), 256, 0, stream>>>(hid, W2_t, NT_, 1024, 4096,
                                              bf2, nullptr, nullptr, x1f, res2,
                                              nullptr, nullptr, nullptr);
  // LN2 -> out
  layernorm_k<<<NT_, 256, 0, stream>>>(res2, g2, be2, out, nullptr, 0);
}

// Round 4
// 268.489 us; speedup vs baseline: 1.7216x; 1.0301x over previous
//
#include <hip/hip_runtime.h>
#include <hip/hip_bf16.h>

#define S_  2048
#define B_  2
#define D_  1024
#define H_  16
#define F_  4096
#define HD_ 64
#define NT_ (S_*B_)   // 4096 tokens

typedef __attribute__((ext_vector_type(8))) short short8;
typedef __attribute__((ext_vector_type(4))) short short4v;
typedef __attribute__((ext_vector_type(4))) float f32x4;

#define MFMA16x16x32(a,b,c) __builtin_amdgcn_mfma_f32_16x16x32_bf16((a),(b),(c),0,0,0)

#define AS1C(p) ((const __attribute__((address_space(1))) void*)(p))
#define AS3(p)  ((__attribute__((address_space(3))) void*)(p))

__device__ __forceinline__ short f2b(float f) {
  union { float f; unsigned u; } x; x.f = f;
  unsigned r = x.u + 0x7FFFu + ((x.u >> 16) & 1u);
  return (short)(r >> 16);
}

// packed f32x2 -> bf16x2 (RNE), one instruction
__device__ __forceinline__ unsigned cvtpk(float a, float b) {
  unsigned r;
  asm("v_cvt_pk_bf16_f32 %0, %1, %2" : "=v"(r) : "v"(a), "v"(b));
  return r;
}
// native 2^x
__device__ __forceinline__ float exp2fast(float x) {
  float r;
  asm("v_exp_f32 %0, %1" : "=v"(r) : "v"(x));
  return r;
}

// ---------------- elementwise fp32 -> bf16 ----------------
__global__ __launch_bounds__(256) void to_bf16_k(const float* __restrict__ in,
                                                 short* __restrict__ out) {
  int i = (blockIdx.x * 256 + threadIdx.x) * 8;
  float4 a = *(const float4*)(in + i);
  float4 b = *(const float4*)(in + i + 4);
  short8 o;
  o[0] = f2b(a.x); o[1] = f2b(a.y); o[2] = f2b(a.z); o[3] = f2b(a.w);
  o[4] = f2b(b.x); o[5] = f2b(b.y); o[6] = f2b(b.z); o[7] = f2b(b.w);
  *(short8*)(out + i) = o;
}

// ---------------- W[K,N] fp32 -> Wt[(n+colbase)][k] bf16 ----------------
__global__ __launch_bounds__(256) void transpose_to_bf16(const float* __restrict__ W,
                                                         short* __restrict__ Wt,
                                                         int K, int N, int colbase, int outK) {
  __shared__ short t[32][33];
  int tx = threadIdx.x & 31, ty = threadIdx.x >> 5;  // ty 0..7
  int kbase = blockIdx.y * 32, nbase = blockIdx.x * 32;
#pragma unroll
  for (int yy = 0; yy < 4; ++yy) {
    int kk = ty + yy * 8;
    t[kk][tx] = f2b(W[(size_t)(kbase + kk) * N + nbase + tx]);
  }
  __syncthreads();
#pragma unroll
  for (int yy = 0; yy < 4; ++yy) {
    int nn = ty + yy * 8;
    Wt[(size_t)(nbase + nn + colbase) * outK + kbase + tx] = t[tx][nn];
  }
}

// ---------------- GEMM: C[M,N] = A[M,K](bf16) @ Bt[N,K]^T(bf16) + epilogue ----------------
// m97 structure: BK=64, global_load_lds width-16, linear LDS dest with
// inverse-swizzled source + XOR-swizzled ds_read (T2, rule #21).
// MODE 0: QKV  (bias q/k/v, q scaled 0.125*log2e, writes q/k [b,h,s,d], v [b,h,d,s] bf16)
// MODE 1: out = acc + bias + resid   (fp32)
// MODE 2: out = relu(acc + bias)     (bf16)
template<int MODE>
__global__ __launch_bounds__(256, 2) void gemm_bt(
    const short* __restrict__ A, const short* __restrict__ Bt,
    int M, int N, int K,
    const float* __restrict__ bias0, const float* __restrict__ bias1,
    const float* __restrict__ bias2,
    const float* __restrict__ resid, float* __restrict__ outf,
    short* __restrict__ outq, short* __restrict__ outk, short* __restrict__ outv) {
  __shared__ __align__(16) short As[128 * 64];
  __shared__ __align__(16) short Bs[128 * 64];
  int tid = threadIdx.x;
  int lane = tid & 63, w = tid >> 6;
  int g = lane >> 4, r = lane & 15;
  int wm = w >> 1, wn = w & 1;
  int row0 = blockIdx.y * 128, col0 = blockIdx.x * 128;

  f32x4 acc[4][4];
#pragma unroll
  for (int m = 0; m < 4; ++m)
#pragma unroll
    for (int n = 0; n < 4; ++n) acc[m][n] = (f32x4){0.f, 0.f, 0.f, 0.f};

  for (int kt = 0; kt < K; kt += 64) {
    // stage 128x64 tiles; LDS dest linear (wave-uniform+lane*16), source
    // column pre-swizzled so a swizzled READ sees the right data
#pragma unroll
    for (int p = 0; p < 4; ++p) {
      int idx = tid + p * 256;
      int row = idx >> 3, c = idx & 7;
      int scol = ((c ^ (row & 7)) << 3);
      __builtin_amdgcn_global_load_lds(AS1C(A  + (size_t)(row0 + row) * K + kt + scol),
                                       AS3(As + idx * 8), 16, 0, 0);
      __builtin_amdgcn_global_load_lds(AS1C(Bt + (size_t)(col0 + row) * K + kt + scol),
                                       AS3(Bs + idx * 8), 16, 0, 0);
    }
    __syncthreads();   // drains vmcnt -> tile visible
    short8 af[4][2], bfr[4][2];
#pragma unroll
    for (int m = 0; m < 4; ++m)
#pragma unroll
      for (int kk = 0; kk < 2; ++kk) {
        int row = wm * 64 + m * 16 + r;
        af[m][kk] = *(const short8*)(As + row * 64 + (((kk * 4 + g) ^ (r & 7)) << 3));
      }
#pragma unroll
    for (int n = 0; n < 4; ++n)
#pragma unroll
      for (int kk = 0; kk < 2; ++kk) {
        int row = wn * 64 + n * 16 + r;
        bfr[n][kk] = *(const short8*)(Bs + row * 64 + (((kk * 4 + g) ^ (r & 7)) << 3));
      }
#pragma unroll
    for (int m = 0; m < 4; ++m)
#pragma unroll
      for (int n = 0; n < 4; ++n)
#pragma unroll
        for (int kk = 0; kk < 2; ++kk)
          acc[m][n] = MFMA16x16x32(af[m][kk], bfr[n][kk], acc[m][n]);
    __syncthreads();   // all waves done reading before next overwrite
  }

  int rb = row0 + wm * 64, cb = col0 + wn * 64;
#pragma unroll
  for (int m = 0; m < 4; ++m) {
#pragma unroll
    for (int n = 0; n < 4; ++n) {
#pragma unroll
      for (int j = 0; j < 4; ++j) {
        int row = rb + m * 16 + g * 4 + j;
        int col = cb + n * 16 + r;
        float v = acc[m][n][j];
        if (MODE == 0) {
          int s = row >> 1, b = row & 1;
          if (col < 1024) {
            // fold log2e so attention works in exp2 domain
            float q = (v + bias0[col]) * (0.125f * 1.44269504088896f);
            int h = col >> 6, hd = col & 63;
            outq[((size_t)(b * H_ + h) * S_ + s) * HD_ + hd] = f2b(q);
          } else if (col < 2048) {
            int c2 = col - 1024;
            float kk = v + bias1[c2];
            int h = c2 >> 6, hd = c2 & 63;
            outk[((size_t)(b * H_ + h) * S_ + s) * HD_ + hd] = f2b(kk);
          } else {
            int c2 = col - 2048;
            float vv = v + bias2[c2];
            int h = c2 >> 6, hd = c2 & 63;
            outv[((size_t)(b * H_ + h) * HD_ + hd) * S_ + s] = f2b(vv);
          }
        } else if (MODE == 1) {
          size_t o = (size_t)row * N + col;
          outf[o] = v + bias0[col] + resid[o];
        } else {
          size_t o = (size_t)row * N + col;
          float t = v + bias0[col];
          outq[o] = f2b(t > 0.f ? t : 0.f);
        }
      }
    }
  }
}

// ---------------- flash attention, swapped-operand + LDS-staged K/V ----------------
// Q,K: [b*H+h][s][d] bf16 (Q pre-scaled by 0.125*log2e), Vt: [b*H+h][d][s] bf16
// S^T = mfma(K, Q): lane owns one q-row -> softmax lane-local (2 shfls/reduce).
// ctx^T = mfma(V^T, P^T). 4 waves x 16 q = 64 q/block; 1024 blocks; KV tile 64,
// double-buffered LDS, XOR swizzle everywhere. LDS = 40960 B -> 4 blocks/CU.
// exp2-domain softmax + defer-max (THR=8) + cvt_pk bf16 packing.
__global__ __launch_bounds__(256, 4) void flash_attn(const short* __restrict__ Q,
                                                     const short* __restrict__ Kb,
                                                     const short* __restrict__ Vt,
                                                     short* __restrict__ ctx) {
  __shared__ __align__(16) short Ks[2][64 * 64];
  __shared__ __align__(16) short Vs[2][64 * 64];
  __shared__ __align__(16) short P[4][16][64];
  int tid = threadIdx.x;
  int lane = tid & 63, w = tid >> 6;
  int g = lane >> 4, r = lane & 15;
  // bijective XCD swizzle: XCD x owns bh in {4x..4x+3} -> 2MB K/V per L2
  int f = blockIdx.x;
  int xcd = f & 7, loc = f >> 3;          // 1024 blocks: loc 0..127
  int bh = xcd * 4 + (loc >> 5);
  int qt = loc & 31;
  const short* qp = Q  + (size_t)bh * S_ * HD_;
  const short* kp = Kb + (size_t)bh * S_ * HD_;
  const short* vp = Vt + (size_t)bh * HD_ * S_;
  int q0 = qt * 64 + w * 16;

  // Q B-operand frags: qf[kk] elem i = Q[q0+r][kk*32+g*8+i]
  short8 qf[2];
#pragma unroll
  for (int kk = 0; kk < 2; ++kk)
    qf[kk] = *(const short8*)(qp + (size_t)(q0 + r) * HD_ + kk * 32 + g * 8);

  f32x4 acc[4];
  float mi = -1e30f, li = 0.f;
#pragma unroll
  for (int db = 0; db < 4; ++db) acc[db] = (f32x4){0.f, 0.f, 0.f, 0.f};

  // prologue: stage tile 0 into buf 0
#pragma unroll
  for (int p = 0; p < 2; ++p) {
    int idx = tid + p * 256;
    int row = idx >> 3, c = idx & 7;
    int scol = ((c ^ (row & 7)) << 3);
    __builtin_amdgcn_global_load_lds(AS1C(kp + (size_t)row * HD_ + scol),
                                     AS3(&Ks[0][0] + idx * 8), 16, 0, 0);
    __builtin_amdgcn_global_load_lds(AS1C(vp + (size_t)row * S_ + scol),
                                     AS3(&Vs[0][0] + idx * 8), 16, 0, 0);
  }
  __syncthreads();

  int cur = 0;
  for (int t = 0; t < S_ / 64; ++t) {
    // prefetch tile t+1 into the other buffer (issue-early; barrier at end drains)
    if (t + 1 < S_ / 64) {
      int kv1 = (t + 1) * 64;
#pragma unroll
      for (int p = 0; p < 2; ++p) {
        int idx = tid + p * 256;
        int row = idx >> 3, c = idx & 7;
        int scol = ((c ^ (row & 7)) << 3);
        __builtin_amdgcn_global_load_lds(AS1C(kp + (size_t)(kv1 + row) * HD_ + scol),
                                         AS3(&Ks[cur ^ 1][0] + idx * 8), 16, 0, 0);
        __builtin_amdgcn_global_load_lds(AS1C(vp + (size_t)row * S_ + kv1 + scol),
                                         AS3(&Vs[cur ^ 1][0] + idx * 8), 16, 0, 0);
      }
    }
    const short* Kc = &Ks[cur][0];
    const short* Vc = &Vs[cur][0];
    // K A-operand frags: kf[kb][kk] elem i = K[t*64+kb*16+r][kk*32+g*8+i]
    short8 kf[4][2];
#pragma unroll
    for (int kb = 0; kb < 4; ++kb)
#pragma unroll
      for (int kk = 0; kk < 2; ++kk) {
        int row = kb * 16 + r;
        kf[kb][kk] = *(const short8*)(Kc + row * 64 + (((kk * 4 + g) ^ (r & 7)) << 3));
      }

    // S^T[kv][q]: st[kb], value at (kv = t*64+kb*16+g*4+j, q = q0+r)
    f32x4 st[4];
#pragma unroll
    for (int kb = 0; kb < 4; ++kb) {
      f32x4 tt = (f32x4){0.f, 0.f, 0.f, 0.f};
      tt = MFMA16x16x32(kf[kb][0], qf[0], tt);
      tt = MFMA16x16x32(kf[kb][1], qf[1], tt);
      st[kb] = tt;
    }

    // online softmax (exp2 domain), defer-max THR=8
    float pm = st[0][0];
#pragma unroll
    for (int kb = 0; kb < 4; ++kb)
#pragma unroll
      for (int j = 0; j < 4; ++j) pm = fmaxf(pm, st[kb][j]);
    pm = fmaxf(pm, __shfl_xor(pm, 16));
    pm = fmaxf(pm, __shfl_xor(pm, 32));
    if (!__all(pm <= mi + 8.0f)) {
      float mn = fmaxf(mi, pm);
      float sc = exp2fast(mi - mn);
      mi = mn;
      li *= sc;
#pragma unroll
      for (int db = 0; db < 4; ++db)
#pragma unroll
        for (int j = 0; j < 4; ++j) acc[db][j] *= sc;
    }
    float rs = 0.f;
#pragma unroll
    for (int kb = 0; kb < 4; ++kb)
#pragma unroll
      for (int j = 0; j < 4; ++j) {
        float p0 = exp2fast(st[kb][j] - mi);
        st[kb][j] = p0;
        rs += p0;
      }
    rs += __shfl_xor(rs, 16);
    rs += __shfl_xor(rs, 32);
    li += rs;

    // P stored [q][kv^swz]: cvt_pk pairs -> one 8B store per kb
#pragma unroll
    for (int kb = 0; kb < 4; ++kb) {
      unsigned w0 = cvtpk(st[kb][0], st[kb][1]);
      unsigned w1 = cvtpk(st[kb][2], st[kb][3]);
      unsigned long long pw = (unsigned long long)w0 | ((unsigned long long)w1 << 32);
      int col = (kb * 16 + g * 4) ^ ((r & 7) << 3);
      *(unsigned long long*)(&P[w][r][0] + col) = pw;
    }

    // V^T A-frags (after softmax: short live range)
    short8 vf[4][2];
#pragma unroll
    for (int db = 0; db < 4; ++db)
#pragma unroll
      for (int ks = 0; ks < 2; ++ks) {
        int row = db * 16 + r;
        vf[db][ks] = *(const short8*)(Vc + row * 64 + (((ks * 4 + g) ^ (r & 7)) << 3));
      }
    short8 pf[2];
#pragma unroll
    for (int ks = 0; ks < 2; ++ks) {
      int col = (ks * 32 + g * 8) ^ ((r & 7) << 3);
      pf[ks] = *(const short8*)(&P[w][r][0] + col);
    }

#pragma unroll
    for (int db = 0; db < 4; ++db) {
      acc[db] = MFMA16x16x32(vf[db][0], pf[0], acc[db]);
      acc[db] = MFMA16x16x32(vf[db][1], pf[1], acc[db]);
    }

    __syncthreads();   // drains prefetch (vmcnt0) + protects buffer swap
    cur ^= 1;
  }

  int b = bh >> 4, h = bh & 15;
  float inv = 1.0f / li;
  int s = q0 + r;
  int token = s * B_ + b;
#pragma unroll
  for (int db = 0; db < 4; ++db) {
    unsigned w0 = cvtpk(acc[db][0] * inv, acc[db][1] * inv);
    unsigned w1 = cvtpk(acc[db][2] * inv, acc[db][3] * inv);
    unsigned long long pw = (unsigned long long)w0 | ((unsigned long long)w1 << 32);
    *(unsigned long long*)(ctx + (size_t)token * D_ + h * 64 + db * 16 + g * 4) = pw;
  }
}

// ---------------- layernorm (row = 1024 fp32), optional bf16 copy ----------------
__global__ __launch_bounds__(256) void layernorm_k(const float* __restrict__ y,
                                                   const float* __restrict__ gm,
                                                   const float* __restrict__ bt,
                                                   float* __restrict__ of,
                                                   short* __restrict__ ob, int writeb) {
  __shared__ float r1[4], r2[4];
  int row = blockIdx.x, tid = threadIdx.x;
  const float* yr = y + (size_t)row * D_;
  float4 v = *(const float4*)(yr + tid * 4);
  float s1 = v.x + v.y + v.z + v.w;
  float s2 = v.x * v.x + v.y * v.y + v.z * v.z + v.w * v.w;
#pragma unroll
  for (int off = 32; off > 0; off >>= 1) {
    s1 += __shfl_xor(s1, off, 64);
    s2 += __shfl_xor(s2, off, 64);
  }
  int wid = tid >> 6;
  if ((tid & 63) == 0) { r1[wid] = s1; r2[wid] = s2; }
  __syncthreads();
  s1 = r1[0] + r1[1] + r1[2] + r1[3];
  s2 = r2[0] + r2[1] + r2[2] + r2[3];
  float mean = s1 * (1.0f / D_);
  float var = s2 * (1.0f / D_) - mean * mean;
  float rstd = rsqrtf(var + 1e-5f);
  float4 gv = *(const float4*)(gm + tid * 4);
  float4 bv = *(const float4*)(bt + tid * 4);
  float o0 = (v.x - mean) * rstd * gv.x + bv.x;
  float o1 = (v.y - mean) * rstd * gv.y + bv.y;
  float o2 = (v.z - mean) * rstd * gv.z + bv.z;
  float o3 = (v.w - mean) * rstd * gv.w + bv.w;
  float4* op = (float4*)(of + (size_t)row * D_ + tid * 4);
  *op = make_float4(o0, o1, o2, o3);
  if (writeb) {
    short4v o;
    o[0] = f2b(o0); o[1] = f2b(o1); o[2] = f2b(o2); o[3] = f2b(o3);
    *(short4v*)(ob + (size_t)row * D_ + tid * 4) = o;
  }
}

extern "C" void kernel_launch(void* const* d_in, const int* in_sizes, int n_in,
                              void* d_out, int out_size, void* d_ws, size_t ws_size,
                              hipStream_t stream) {
  const float* src = (const float*)d_in[0];
  const float* Wq  = (const float*)d_in[1];
  const float* bq  = (const float*)d_in[2];
  const float* Wk  = (const float*)d_in[3];
  const float* bk  = (const float*)d_in[4];
  const float* Wv  = (const float*)d_in[5];
  const float* bv  = (const float*)d_in[6];
  const float* Wo  = (const float*)d_in[7];
  const float* bo  = (const float*)d_in[8];
  const float* g1  = (const float*)d_in[9];
  const float* be1 = (const float*)d_in[10];
  const float* W1  = (const float*)d_in[11];
  const float* bf1 = (const float*)d_in[12];
  const float* W2  = (const float*)d_in[13];
  const float* bf2 = (const float*)d_in[14];
  const float* g2  = (const float*)d_in[15];
  const float* be2 = (const float*)d_in[16];
  float* out = (float*)d_out;
  char* ws = (char*)d_ws;

  // workspace layout (bytes), lifetime-overlapped; total 104 MiB
  short* Wqkv_t = (short*)(ws + 0);          // 6 MiB  [3072][1024]
  short* Wo_t   = (short*)(ws + 6291456);    // 2 MiB  [1024][1024]
  short* W1_t   = (short*)(ws + 8388608);    // 8 MiB  [4096][1024]
  short* W2_t   = (short*)(ws + 16777216);   // 8 MiB  [1024][4096]
  short* xb     = (short*)(ws + 25165824);   // 8 MiB  src bf16
  short* ctx    = (short*)(ws + 33554432);   // 8 MiB
  float* res1   = (float*)(ws + 41943040);   // 16 MiB
  short* hid    = (short*)(ws + 25165824);   // 32 MiB, overlays xb|ctx|res1 (all dead)
  short* qb_    = (short*)(ws + 58720256);   // 8 MiB
  short* kb_    = (short*)(ws + 67108864);   // 8 MiB
  float* res2   = (float*)(ws + 58720256);   // 16 MiB, overlays q|k (dead)
  short* vb_    = (short*)(ws + 75497472);   // 8 MiB
  float* x1f    = (float*)(ws + 83886080);   // 16 MiB
  short* x1b    = (short*)(ws + 100663296);  // 8 MiB   (end: 109051904)

  to_bf16_k<<<2048, 256, 0, stream>>>(src, xb);

  transpose_to_bf16<<<dim3(32, 32),  256, 0, stream>>>(Wq, Wqkv_t, 1024, 1024, 0,    1024);
  transpose_to_bf16<<<dim3(32, 32),  256, 0, stream>>>(Wk, Wqkv_t, 1024, 1024, 1024, 1024);
  transpose_to_bf16<<<dim3(32, 32),  256, 0, stream>>>(Wv, Wqkv_t, 1024, 1024, 2048, 1024);
  transpose_to_bf16<<<dim3(32, 32),  256, 0, stream>>>(Wo, Wo_t,   1024, 1024, 0,    1024);
  transpose_to_bf16<<<dim3(128, 32), 256, 0, stream>>>(W1, W1_t,   1024, 4096, 0,    1024);
  transpose_to_bf16<<<dim3(32, 128), 256, 0, stream>>>(W2, W2_t,   4096, 1024, 0,    4096);

  // QKV projection (M=4096, N=3072, K=1024)
  gemm_bt<0><<<dim3(24, 32), 256, 0, stream>>>(xb, Wqkv_t, NT_, 3072, 1024,
                                               bq, bk, bv, nullptr, nullptr, qb_, kb_, vb_);
  // attention (1024 blocks, XCD-swizzled, 64 q/block)
  flash_attn<<<1024, 256, 0, stream>>>(qb_, kb_, vb_, ctx);
  // out-proj + residual(src) -> res1
  gemm_bt<1><<<dim3(8, 32), 256, 0, stream>>>(ctx, Wo_t, NT_, 1024, 1024,
                                              bo, nullptr, nullptr, src, res1,
                                              nullptr, nullptr, nullptr);
  // LN1 -> x1f (fp32) + x1b (bf16)
  layernorm_k<<<NT_, 256, 0, stream>>>(res1, g1, be1, x1f, x1b, 1);
  // FFN1 + ReLU -> hid (bf16, M=4096, N=4096, K=1024)
  gemm_bt<2><<<dim3(32, 32), 256, 0, stream>>>(x1b, W1_t, NT_, 4096, 1024,
                                               bf1, nullptr, nullptr, nullptr, nullptr,
                                               hid, nullptr, nullptr);
  // FFN2 + residual(x1f) -> res2 (M=4096, N=1024, K=4096)
  gemm_bt<1><<<dim3(8, 32), 256, 0, stream>>>(hid, W2_t, NT_, 1024, 4096,
                                              bf2, nullptr, nullptr, x1f, res2,
                                              nullptr, nullptr, nullptr);
  // LN2 -> out
  layernorm_k<<<NT_, 256, 0, stream>>>(res2, g2, be2, out, nullptr, 0);
}

// Round 6
// 240.206 us; speedup vs baseline: 1.9243x; 1.1177x over previous
//
#include <hip/hip_runtime.h>
#include <hip/hip_bf16.h>

#define S_  2048
#define B_  2
#define D_  1024
#define H_  16
#define F_  4096
#define HD_ 64
#define NT_ (S_*B_)   // 4096 tokens

typedef __attribute__((ext_vector_type(8))) short short8;
typedef __attribute__((ext_vector_type(4))) short short4v;
typedef __attribute__((ext_vector_type(4))) float f32x4;

#define MFMA16x16x32(a,b,c) __builtin_amdgcn_mfma_f32_16x16x32_bf16((a),(b),(c),0,0,0)

#define AS1C(p) ((const __attribute__((address_space(1))) void*)(p))
#define AS3(p)  ((__attribute__((address_space(3))) void*)(p))

__device__ __forceinline__ short f2b(float f) {
  union { float f; unsigned u; } x; x.f = f;
  unsigned r = x.u + 0x7FFFu + ((x.u >> 16) & 1u);
  return (short)(r >> 16);
}
__device__ __forceinline__ float b2f(short u) {
  union { unsigned u; float f; } x; x.u = ((unsigned)(unsigned short)u) << 16;
  return x.f;
}
// packed f32x2 -> bf16x2 (RNE), one instruction
__device__ __forceinline__ unsigned cvtpk(float a, float b) {
  unsigned r;
  asm("v_cvt_pk_bf16_f32 %0, %1, %2" : "=v"(r) : "v"(a), "v"(b));
  return r;
}
// native 2^x
__device__ __forceinline__ float exp2fast(float x) {
  float r;
  asm("v_exp_f32 %0, %1" : "=v"(r) : "v"(x));
  return r;
}

// ---------------- elementwise fp32 -> bf16 ----------------
__global__ __launch_bounds__(256) void to_bf16_k(const float* __restrict__ in,
                                                 short* __restrict__ out) {
  int i = (blockIdx.x * 256 + threadIdx.x) * 8;
  float4 a = *(const float4*)(in + i);
  float4 b = *(const float4*)(in + i + 4);
  short8 o;
  o[0] = f2b(a.x); o[1] = f2b(a.y); o[2] = f2b(a.z); o[3] = f2b(a.w);
  o[4] = f2b(b.x); o[5] = f2b(b.y); o[6] = f2b(b.z); o[7] = f2b(b.w);
  *(short8*)(out + i) = o;
}

// ---------------- W[K,N] fp32 -> Wt[(n+colbase)][k] bf16 ----------------
__global__ __launch_bounds__(256) void transpose_to_bf16(const float* __restrict__ W,
                                                         short* __restrict__ Wt,
                                                         int K, int N, int colbase, int outK) {
  __shared__ short t[32][33];
  int tx = threadIdx.x & 31, ty = threadIdx.x >> 5;  // ty 0..7
  int kbase = blockIdx.y * 32, nbase = blockIdx.x * 32;
#pragma unroll
  for (int yy = 0; yy < 4; ++yy) {
    int kk = ty + yy * 8;
    t[kk][tx] = f2b(W[(size_t)(kbase + kk) * N + nbase + tx]);
  }
  __syncthreads();
#pragma unroll
  for (int yy = 0; yy < 4; ++yy) {
    int nn = ty + yy * 8;
    Wt[(size_t)(nbase + nn + colbase) * outK + kbase + tx] = t[tx][nn];
  }
}

// ---------------- GEMM: C[M,N] = A[M,K](bf16) @ Bt[N,K]^T(bf16) + epilogue ----------------
// m97 structure: BK=64, global_load_lds width-16, linear LDS dest with
// inverse-swizzled source + XOR-swizzled ds_read (T2, rule #21).
// Grid may be 3D: blockIdx.z = K-split index; K = per-block reduction length,
// lda = full row stride of A and Bt. Bijective XCD chunk-swizzle on flat id.
// MODE 0: QKV  (bias q/k/v, q scaled 0.125*log2e, writes q/k [b,h,s,d], v [b,h,d,s] bf16)
// MODE 2: out = relu(acc + bias)     (bf16)
// MODE 3: outf[z*M*N + row*N + col] = acc   (fp32 partial, no bias)
template<int MODE>
__global__ __launch_bounds__(256, 2) void gemm_bt(
    const short* __restrict__ A, const short* __restrict__ Bt,
    int M, int N, int K, int lda,
    const float* __restrict__ bias0, const float* __restrict__ bias1,
    const float* __restrict__ bias2,
    float* __restrict__ outf,
    short* __restrict__ outq, short* __restrict__ outk, short* __restrict__ outv) {
  __shared__ __align__(16) short As[128 * 64];
  __shared__ __align__(16) short Bs[128 * 64];
  int tid = threadIdx.x;
  int lane = tid & 63, w = tid >> 6;
  int g = lane >> 4, r = lane & 15;
  int wm = w >> 1, wn = w & 1;

  // bijective XCD chunk swizzle (nwg % 8 == 0 for all launches)
  int gx = gridDim.x, gy = gridDim.y;
  int nwg = gx * gy * gridDim.z;
  int flat = (blockIdx.z * gy + blockIdx.y) * gx + blockIdx.x;
  int cpx = nwg >> 3;
  int swz = (flat & 7) * cpx + (flat >> 3);
  int z = swz / (gx * gy);
  int rem = swz - z * gx * gy;
  int row0 = (rem / gx) * 128;
  int col0 = (rem % gx) * 128;
  size_t koff = (size_t)z * K;

  f32x4 acc[4][4];
#pragma unroll
  for (int m = 0; m < 4; ++m)
#pragma unroll
    for (int n = 0; n < 4; ++n) acc[m][n] = (f32x4){0.f, 0.f, 0.f, 0.f};

  for (int kt = 0; kt < K; kt += 64) {
    // stage 128x64 tiles; LDS dest linear (wave-uniform+lane*16), source
    // column pre-swizzled so a swizzled READ sees the right data
#pragma unroll
    for (int p = 0; p < 4; ++p) {
      int idx = tid + p * 256;
      int row = idx >> 3, c = idx & 7;
      int scol = ((c ^ (row & 7)) << 3);
      __builtin_amdgcn_global_load_lds(AS1C(A  + (size_t)(row0 + row) * lda + koff + kt + scol),
                                       AS3(As + idx * 8), 16, 0, 0);
      __builtin_amdgcn_global_load_lds(AS1C(Bt + (size_t)(col0 + row) * lda + koff + kt + scol),
                                       AS3(Bs + idx * 8), 16, 0, 0);
    }
    __syncthreads();   // drains vmcnt -> tile visible
    short8 af[4][2], bfr[4][2];
#pragma unroll
    for (int m = 0; m < 4; ++m)
#pragma unroll
      for (int kk = 0; kk < 2; ++kk) {
        int row = wm * 64 + m * 16 + r;
        af[m][kk] = *(const short8*)(As + row * 64 + (((kk * 4 + g) ^ (r & 7)) << 3));
      }
#pragma unroll
    for (int n = 0; n < 4; ++n)
#pragma unroll
      for (int kk = 0; kk < 2; ++kk) {
        int row = wn * 64 + n * 16 + r;
        bfr[n][kk] = *(const short8*)(Bs + row * 64 + (((kk * 4 + g) ^ (r & 7)) << 3));
      }
#pragma unroll
    for (int m = 0; m < 4; ++m)
#pragma unroll
      for (int n = 0; n < 4; ++n)
#pragma unroll
        for (int kk = 0; kk < 2; ++kk)
          acc[m][n] = MFMA16x16x32(af[m][kk], bfr[n][kk], acc[m][n]);
    __syncthreads();   // all waves done reading before next overwrite
  }

  int rb = row0 + wm * 64, cb = col0 + wn * 64;
#pragma unroll
  for (int m = 0; m < 4; ++m) {
#pragma unroll
    for (int n = 0; n < 4; ++n) {
#pragma unroll
      for (int j = 0; j < 4; ++j) {
        int row = rb + m * 16 + g * 4 + j;
        int col = cb + n * 16 + r;
        float v = acc[m][n][j];
        if (MODE == 0) {
          int s = row >> 1, b = row & 1;
          if (col < 1024) {
            // fold log2e so attention works in exp2 domain
            float q = (v + bias0[col]) * (0.125f * 1.44269504088896f);
            int h = col >> 6, hd = col & 63;
            outq[((size_t)(b * H_ + h) * S_ + s) * HD_ + hd] = f2b(q);
          } else if (col < 2048) {
            int c2 = col - 1024;
            float kk = v + bias1[c2];
            int h = c2 >> 6, hd = c2 & 63;
            outk[((size_t)(b * H_ + h) * S_ + s) * HD_ + hd] = f2b(kk);
          } else {
            int c2 = col - 2048;
            float vv = v + bias2[c2];
            int h = c2 >> 6, hd = c2 & 63;
            outv[((size_t)(b * H_ + h) * HD_ + hd) * S_ + s] = f2b(vv);
          }
        } else if (MODE == 2) {
          size_t o = (size_t)row * N + col;
          float t = v + bias0[col];
          outq[o] = f2b(t > 0.f ? t : 0.f);
        } else {
          outf[(size_t)z * M * N + (size_t)row * N + col] = v;
        }
      }
    }
  }
}

// ---------------- flash attention, swapped-operand + LDS-staged K/V ----------------
// Q,K: [b*H+h][s][d] bf16 (Q pre-scaled by 0.125*log2e), Vt: [b*H+h][d][s] bf16
// S^T = mfma(K, Q): lane owns one q-row -> softmax lane-local (2 shfls/reduce).
// ctx^T = mfma(V^T, P^T). 4 waves x 16 q = 64 q/block; 1024 blocks; KV tile 64,
// double-buffered LDS, XOR swizzle everywhere. LDS = 40960 B -> 4 blocks/CU.
// exp2-domain softmax + defer-max (THR=8) + cvt_pk bf16 packing.
__global__ __launch_bounds__(256, 4) void flash_attn(const short* __restrict__ Q,
                                                     const short* __restrict__ Kb,
                                                     const short* __restrict__ Vt,
                                                     short* __restrict__ ctx) {
  __shared__ __align__(16) short Ks[2][64 * 64];
  __shared__ __align__(16) short Vs[2][64 * 64];
  __shared__ __align__(16) short P[4][16][64];
  int tid = threadIdx.x;
  int lane = tid & 63, w = tid >> 6;
  int g = lane >> 4, r = lane & 15;
  // bijective XCD swizzle: XCD x owns bh in {4x..4x+3} -> 2MB K/V per L2
  int f = blockIdx.x;
  int xcd = f & 7, loc = f >> 3;          // 1024 blocks: loc 0..127
  int bh = xcd * 4 + (loc >> 5);
  int qt = loc & 31;
  const short* qp = Q  + (size_t)bh * S_ * HD_;
  const short* kp = Kb + (size_t)bh * S_ * HD_;
  const short* vp = Vt + (size_t)bh * HD_ * S_;
  int q0 = qt * 64 + w * 16;

  // Q B-operand frags: qf[kk] elem i = Q[q0+r][kk*32+g*8+i]
  short8 qf[2];
#pragma unroll
  for (int kk = 0; kk < 2; ++kk)
    qf[kk] = *(const short8*)(qp + (size_t)(q0 + r) * HD_ + kk * 32 + g * 8);

  f32x4 acc[4];
  float mi = -1e30f, li = 0.f;
#pragma unroll
  for (int db = 0; db < 4; ++db) acc[db] = (f32x4){0.f, 0.f, 0.f, 0.f};

  // prologue: stage tile 0 into buf 0
#pragma unroll
  for (int p = 0; p < 2; ++p) {
    int idx = tid + p * 256;
    int row = idx >> 3, c = idx & 7;
    int scol = ((c ^ (row & 7)) << 3);
    __builtin_amdgcn_global_load_lds(AS1C(kp + (size_t)row * HD_ + scol),
                                     AS3(&Ks[0][0] + idx * 8), 16, 0, 0);
    __builtin_amdgcn_global_load_lds(AS1C(vp + (size_t)row * S_ + scol),
                                     AS3(&Vs[0][0] + idx * 8), 16, 0, 0);
  }
  __syncthreads();

  int cur = 0;
  for (int t = 0; t < S_ / 64; ++t) {
    // prefetch tile t+1 into the other buffer (issue-early; barrier at end drains)
    if (t + 1 < S_ / 64) {
      int kv1 = (t + 1) * 64;
#pragma unroll
      for (int p = 0; p < 2; ++p) {
        int idx = tid + p * 256;
        int row = idx >> 3, c = idx & 7;
        int scol = ((c ^ (row & 7)) << 3);
        __builtin_amdgcn_global_load_lds(AS1C(kp + (size_t)(kv1 + row) * HD_ + scol),
                                         AS3(&Ks[cur ^ 1][0] + idx * 8), 16, 0, 0);
        __builtin_amdgcn_global_load_lds(AS1C(vp + (size_t)row * S_ + kv1 + scol),
                                         AS3(&Vs[cur ^ 1][0] + idx * 8), 16, 0, 0);
      }
    }
    const short* Kc = &Ks[cur][0];
    const short* Vc = &Vs[cur][0];
    // K A-operand frags: kf[kb][kk] elem i = K[t*64+kb*16+r][kk*32+g*8+i]
    short8 kf[4][2];
#pragma unroll
    for (int kb = 0; kb < 4; ++kb)
#pragma unroll
      for (int kk = 0; kk < 2; ++kk) {
        int row = kb * 16 + r;
        kf[kb][kk] = *(const short8*)(Kc + row * 64 + (((kk * 4 + g) ^ (r & 7)) << 3));
      }

    // S^T[kv][q]: st[kb], value at (kv = t*64+kb*16+g*4+j, q = q0+r)
    f32x4 st[4];
#pragma unroll
    for (int kb = 0; kb < 4; ++kb) {
      f32x4 tt = (f32x4){0.f, 0.f, 0.f, 0.f};
      tt = MFMA16x16x32(kf[kb][0], qf[0], tt);
      tt = MFMA16x16x32(kf[kb][1], qf[1], tt);
      st[kb] = tt;
    }

    // online softmax (exp2 domain), defer-max THR=8
    float pm = st[0][0];
#pragma unroll
    for (int kb = 0; kb < 4; ++kb)
#pragma unroll
      for (int j = 0; j < 4; ++j) pm = fmaxf(pm, st[kb][j]);
    pm = fmaxf(pm, __shfl_xor(pm, 16));
    pm = fmaxf(pm, __shfl_xor(pm, 32));
    if (!__all(pm <= mi + 8.0f)) {
      float mn = fmaxf(mi, pm);
      float sc = exp2fast(mi - mn);
      mi = mn;
      li *= sc;
#pragma unroll
      for (int db = 0; db < 4; ++db)
#pragma unroll
        for (int j = 0; j < 4; ++j) acc[db][j] *= sc;
    }
    float rs = 0.f;
#pragma unroll
    for (int kb = 0; kb < 4; ++kb)
#pragma unroll
      for (int j = 0; j < 4; ++j) {
        float p0 = exp2fast(st[kb][j] - mi);
        st[kb][j] = p0;
        rs += p0;
      }
    rs += __shfl_xor(rs, 16);
    rs += __shfl_xor(rs, 32);
    li += rs;

    // P stored [q][kv^swz]: cvt_pk pairs -> one 8B store per kb
#pragma unroll
    for (int kb = 0; kb < 4; ++kb) {
      unsigned w0 = cvtpk(st[kb][0], st[kb][1]);
      unsigned w1 = cvtpk(st[kb][2], st[kb][3]);
      unsigned long long pw = (unsigned long long)w0 | ((unsigned long long)w1 << 32);
      int col = (kb * 16 + g * 4) ^ ((r & 7) << 3);
      *(unsigned long long*)(&P[w][r][0] + col) = pw;
    }

    // V^T A-frags (after softmax: short live range)
    short8 vf[4][2];
#pragma unroll
    for (int db = 0; db < 4; ++db)
#pragma unroll
      for (int ks = 0; ks < 2; ++ks) {
        int row = db * 16 + r;
        vf[db][ks] = *(const short8*)(Vc + row * 64 + (((ks * 4 + g) ^ (r & 7)) << 3));
      }
    short8 pf[2];
#pragma unroll
    for (int ks = 0; ks < 2; ++ks) {
      int col = (ks * 32 + g * 8) ^ ((r & 7) << 3);
      pf[ks] = *(const short8*)(&P[w][r][0] + col);
    }

#pragma unroll
    for (int db = 0; db < 4; ++db) {
      acc[db] = MFMA16x16x32(vf[db][0], pf[0], acc[db]);
      acc[db] = MFMA16x16x32(vf[db][1], pf[1], acc[db]);
    }

    __syncthreads();   // drains prefetch (vmcnt0) + protects buffer swap
    cur ^= 1;
  }

  int b = bh >> 4, h = bh & 15;
  float inv = 1.0f / li;
  int s = q0 + r;
  int token = s * B_ + b;
#pragma unroll
  for (int db = 0; db < 4; ++db) {
    unsigned w0 = cvtpk(acc[db][0] * inv, acc[db][1] * inv);
    unsigned w1 = cvtpk(acc[db][2] * inv, acc[db][3] * inv);
    unsigned long long pw = (unsigned long long)w0 | ((unsigned long long)w1 << 32);
    *(unsigned long long*)(ctx + (size_t)token * D_ + h * 64 + db * 16 + g * 4) = pw;
  }
}

// ---------------- fused split-K reduce + bias + residual + layernorm ----------------
// x = p0 + p1 + bias + resid;  LN(x) -> fp32 out (WF) and/or bf16 out (WB)
template<int RESBF16, int WF, int WB>
__global__ __launch_bounds__(256) void layernorm_fused(
    const float* __restrict__ p0, const float* __restrict__ p1,
    const float* __restrict__ bias,
    const float* __restrict__ residf, const short* __restrict__ residb,
    const float* __restrict__ gm, const float* __restrict__ bt,
    float* __restrict__ of, short* __restrict__ ob) {
  __shared__ float r1[4], r2[4];
  int row = blockIdx.x, tid = threadIdx.x;
  size_t base = (size_t)row * D_ + tid * 4;
  float4 a = *(const float4*)(p0 + base);
  float4 b = *(const float4*)(p1 + base);
  float4 bi = *(const float4*)(bias + tid * 4);
  float4 v;
  if (RESBF16) {
    short4v rb = *(const short4v*)(residb + base);
    v.x = a.x + b.x + bi.x + b2f(rb[0]);
    v.y = a.y + b.y + bi.y + b2f(rb[1]);
    v.z = a.z + b.z + bi.z + b2f(rb[2]);
    v.w = a.w + b.w + bi.w + b2f(rb[3]);
  } else {
    float4 rf = *(const float4*)(residf + base);
    v.x = a.x + b.x + bi.x + rf.x;
    v.y = a.y + b.y + bi.y + rf.y;
    v.z = a.z + b.z + bi.z + rf.z;
    v.w = a.w + b.w + bi.w + rf.w;
  }
  float s1 = v.x + v.y + v.z + v.w;
  float s2 = v.x * v.x + v.y * v.y + v.z * v.z + v.w * v.w;
#pragma unroll
  for (int off = 32; off > 0; off >>= 1) {
    s1 += __shfl_xor(s1, off, 64);
    s2 += __shfl_xor(s2, off, 64);
  }
  int wid = tid >> 6;
  if ((tid & 63) == 0) { r1[wid] = s1; r2[wid] = s2; }
  __syncthreads();
  s1 = r1[0] + r1[1] + r1[2] + r1[3];
  s2 = r2[0] + r2[1] + r2[2] + r2[3];
  float mean = s1 * (1.0f / D_);
  float var = s2 * (1.0f / D_) - mean * mean;
  float rstd = rsqrtf(var + 1e-5f);
  float4 gv = *(const float4*)(gm + tid * 4);
  float4 bv = *(const float4*)(bt + tid * 4);
  float o0 = (v.x - mean) * rstd * gv.x + bv.x;
  float o1 = (v.y - mean) * rstd * gv.y + bv.y;
  float o2 = (v.z - mean) * rstd * gv.z + bv.z;
  float o3 = (v.w - mean) * rstd * gv.w + bv.w;
  if (WF) *(float4*)(of + base) = make_float4(o0, o1, o2, o3);
  if (WB) {
    short4v o;
    o[0] = f2b(o0); o[1] = f2b(o1); o[2] = f2b(o2); o[3] = f2b(o3);
    *(short4v*)(ob + base) = o;
  }
}

extern "C" void kernel_launch(void* const* d_in, const int* in_sizes, int n_in,
                              void* d_out, int out_size, void* d_ws, size_t ws_size,
                              hipStream_t stream) {
  const float* src = (const float*)d_in[0];
  const float* Wq  = (const float*)d_in[1];
  const float* bq  = (const float*)d_in[2];
  const float* Wk  = (const float*)d_in[3];
  const float* bk  = (const float*)d_in[4];
  const float* Wv  = (const float*)d_in[5];
  const float* bv  = (const float*)d_in[6];
  const float* Wo  = (const float*)d_in[7];
  const float* bo  = (const float*)d_in[8];
  const float* g1  = (const float*)d_in[9];
  const float* be1 = (const float*)d_in[10];
  const float* W1  = (const float*)d_in[11];
  const float* bf1 = (const float*)d_in[12];
  const float* W2  = (const float*)d_in[13];
  const float* bf2 = (const float*)d_in[14];
  const float* g2  = (const float*)d_in[15];
  const float* be2 = (const float*)d_in[16];
  float* out = (float*)d_out;
  char* ws = (char*)d_ws;

  const size_t MiB = 1024 * 1024;
  // workspace layout (96 MiB, lifetime-overlapped)
  short* Wqkv_t = (short*)(ws + 0 * MiB);    // 6 MiB  [3072][1024]
  short* Wo_t   = (short*)(ws + 6 * MiB);    // 2 MiB  [1024][1024]
  short* W1_t   = (short*)(ws + 8 * MiB);    // 8 MiB  [4096][1024]
  short* W2_t   = (short*)(ws + 16 * MiB);   // 8 MiB  [1024][4096]
  short* xb     = (short*)(ws + 24 * MiB);   // 8 MiB  src bf16 (dead after QKV)
  short* x1b    = (short*)(ws + 24 * MiB);   // 8 MiB  overlays xb
  short* ctx    = (short*)(ws + 32 * MiB);   // 8 MiB  (dead after out-proj)
  short* qb_    = (short*)(ws + 40 * MiB);   // 8 MiB
  short* kb_    = (short*)(ws + 48 * MiB);   // 8 MiB
  short* vb_    = (short*)(ws + 56 * MiB);   // 8 MiB
  short* hid    = (short*)(ws + 32 * MiB);   // 32 MiB overlays ctx|qb_|kb_|vb_ (dead by FFN1)
  float* part   = (float*)(ws + 64 * MiB);   // 32 MiB [2][4096][1024] fp32 partials (reused)
  float* part1  = part + (size_t)NT_ * D_;

  to_bf16_k<<<2048, 256, 0, stream>>>(src, xb);

  transpose_to_bf16<<<dim3(32, 32),  256, 0, stream>>>(Wq, Wqkv_t, 1024, 1024, 0,    1024);
  transpose_to_bf16<<<dim3(32, 32),  256, 0, stream>>>(Wk, Wqkv_t, 1024, 1024, 1024, 1024);
  transpose_to_bf16<<<dim3(32, 32),  256, 0, stream>>>(Wv, Wqkv_t, 1024, 1024, 2048, 1024);
  transpose_to_bf16<<<dim3(32, 32),  256, 0, stream>>>(Wo, Wo_t,   1024, 1024, 0,    1024);
  transpose_to_bf16<<<dim3(128, 32), 256, 0, stream>>>(W1, W1_t,   1024, 4096, 0,    1024);
  transpose_to_bf16<<<dim3(32, 128), 256, 0, stream>>>(W2, W2_t,   4096, 1024, 0,    4096);

  // QKV projection (M=4096, N=3072, K=1024)
  gemm_bt<0><<<dim3(24, 32, 1), 256, 0, stream>>>(xb, Wqkv_t, NT_, 3072, 1024, 1024,
                                                  bq, bk, bv, nullptr, qb_, kb_, vb_);
  // attention (1024 blocks, XCD-swizzled, 64 q/block)
  flash_attn<<<1024, 256, 0, stream>>>(qb_, kb_, vb_, ctx);
  // out-proj, split-K=2 -> fp32 partials
  gemm_bt<3><<<dim3(8, 32, 2), 256, 0, stream>>>(ctx, Wo_t, NT_, 1024, 512, 1024,
                                                 nullptr, nullptr, nullptr, part,
                                                 nullptr, nullptr, nullptr);
  // LN1 = LN(p0+p1+bo+src) -> x1b (bf16)
  layernorm_fused<0, 0, 1><<<NT_, 256, 0, stream>>>(part, part1, bo, src, nullptr,
                                                    g1, be1, nullptr, x1b);
  // FFN1 + ReLU -> hid (bf16, M=4096, N=4096, K=1024)
  gemm_bt<2><<<dim3(32, 32, 1), 256, 0, stream>>>(x1b, W1_t, NT_, 4096, 1024, 1024,
                                                  bf1, nullptr, nullptr, nullptr,
                                                  hid, nullptr, nullptr);
  // FFN2, split-K=2 (K=4096 -> 2048 each) -> fp32 partials
  gemm_bt<3><<<dim3(8, 32, 2), 256, 0, stream>>>(hid, W2_t, NT_, 1024, 2048, 4096,
                                                 nullptr, nullptr, nullptr, part,
                                                 nullptr, nullptr, nullptr);
  // LN2 = LN(p0+p1+bf2+x1b) -> out (fp32)
  layernorm_fused<1, 1, 0><<<NT_, 256, 0, stream>>>(part, part1, bf2, nullptr, x1b,
                                                    g2, be2, out, nullptr);
}